// Round 6
// baseline (122.888 us; speedup 1.0000x reference)
//
#include <hip/hip_runtime.h>
#include <hip/hip_bf16.h>

typedef _Float16 half8 __attribute__((ext_vector_type(8)));
typedef unsigned short ushort8 __attribute__((ext_vector_type(8)));
typedef float floatx4 __attribute__((ext_vector_type(4)));

#define B_ 4
#define C_ 256
#define N_ 4096
#define NT 32            // 128-wide tiles per dim
#define TRI 528          // NT*(NT+1)/2 triangular tiles per batch

// workspace layout (bytes)
#define OFF_FN    ((size_t)0)                     // 4*4096*256 fp16 = 8 MB
#define OFF_PROB  ((size_t)(8u << 20))            // 16384 fp32 = 64 KB
#define OFF_PART  (OFF_PROB + 65536)              // 4096 fp32 block partials = 16 KB
#define OFF_TOP   ((size_t)(16u << 20))           // 16384 rows x 32 jtiles x 8 u32 = 16 MB

__device__ __forceinline__ void gl_lds16(const void* g, void* l) {
    __builtin_amdgcn_global_load_lds(
        (const __attribute__((address_space(1))) void*)g,
        (__attribute__((address_space(3))) void*)l,
        16, 0, 0);
}

__device__ __forceinline__ void pipe_barrier() {
    __builtin_amdgcn_sched_barrier(0);
    __builtin_amdgcn_s_barrier();
    __builtin_amdgcn_sched_barrier(0);
}

__device__ __forceinline__ void cas(uint32_t& a, uint32_t& b) {
    uint32_t hi = max(a, b); b = min(a, b); a = hi;
}

// Batcher odd-even mergesort, 8 elems, descending (19 CAS)
__device__ __forceinline__ void sort8(uint32_t v[8]) {
    cas(v[0],v[1]); cas(v[2],v[3]); cas(v[4],v[5]); cas(v[6],v[7]);
    cas(v[0],v[2]); cas(v[1],v[3]); cas(v[4],v[6]); cas(v[5],v[7]);
    cas(v[1],v[2]); cas(v[5],v[6]);
    cas(v[0],v[4]); cas(v[1],v[5]); cas(v[2],v[6]); cas(v[3],v[7]);
    cas(v[2],v[4]); cas(v[3],v[5]);
    cas(v[1],v[2]); cas(v[3],v[4]); cas(v[5],v[6]);
}

// r, n desc-sorted -> r = top-8 of union, desc-sorted (8 max + 12 CAS)
__device__ __forceinline__ void merge8(uint32_t r[8], const uint32_t n[8]) {
    uint32_t m[8];
#pragma unroll
    for (int i = 0; i < 8; ++i) m[i] = max(r[i], n[7 - i]);   // bitonic
    cas(m[0],m[4]); cas(m[1],m[5]); cas(m[2],m[6]); cas(m[3],m[7]);
    cas(m[0],m[2]); cas(m[1],m[3]); cas(m[4],m[6]); cas(m[5],m[7]);
    cas(m[0],m[1]); cas(m[2],m[3]); cas(m[4],m[5]); cas(m[6],m[7]);
#pragma unroll
    for (int i = 0; i < 8; ++i) r[i] = m[i];
}

// ---------------- Kernel 1: fused prep — reads feats once ----------------
#define TS 68
__global__ __launch_bounds__(256) void prep_kernel(const float* __restrict__ feats,
                                                   const float* __restrict__ logits,
                                                   _Float16* __restrict__ fn,
                                                   float* __restrict__ prob) {
    __shared__ __align__(16) float T[C_ * TS];
    __shared__ float S[256];
    __shared__ float I[64];

    const int t  = threadIdx.x;
    const int b  = blockIdx.x >> 6;
    const int i0 = (blockIdx.x & 63) * 64;
    const float* fb = feats + (size_t)b * C_ * N_;

#pragma unroll
    for (int k = 0; k < 16; ++k) {
        int ch = t + k * 256;
        int row = ch >> 4, col4 = ch & 15;
        float4 v = *(const float4*)(fb + (size_t)row * N_ + i0 + col4 * 4);
        *(float4*)&T[row * TS + col4 * 4] = v;
    }
    __syncthreads();
    {
        int i = t & 63, cq = t >> 6;
        float ss = 0.f;
#pragma unroll 8
        for (int j = 0; j < 64; ++j) { float v = T[(cq * 64 + j) * TS + i]; ss += v * v; }
        S[cq * 64 + i] = ss;
    }
    __syncthreads();
    if (t < 64) {
        float ss = S[t] + S[64 + t] + S[128 + t] + S[192 + t];
        I[t] = 1.f / fmaxf(sqrtf(ss), 1e-12f);
        float lg = logits[b * N_ + i0 + t];
        prob[b * N_ + i0 + t] = 1.f / (1.f + expf(-lg));
    }
    __syncthreads();
    {
        int i = t >> 2, chunk = t & 3;
        float s = I[i];
        _Float16* fr = fn + ((size_t)(b * N_ + i0 + i)) * C_ + chunk * 64;
#pragma unroll
        for (int v8 = 0; v8 < 8; ++v8) {
            half8 h;
#pragma unroll
            for (int e = 0; e < 8; ++e)
                h[e] = (_Float16)(T[(chunk * 64 + v8 * 8 + e) * TS + i] * s);
            *(half8*)(fr + v8 * 8) = h;
        }
    }
}

// ---------------- Kernel 2: triangular MFMA gram tile + dual-scan top-8 ----------------
// T3/T4-lite K-loop: BK=32, two 16KB buffers, depth-2 prefetch, COUNTED vmcnt(4)
// (never 0 in steady state) + raw s_barrier. R1's pipelining failed because
// __syncthreads drained vmcnt to 0 every step; the counted wait keeps 8 loads in
// flight across barriers. LDS layout per buffer: 128B line = row-pair x 4 chunks,
// slot = ((row&1)<<2|chunk) ^ (R&7)  (R2-proven conflict-free: 2 lanes/quad).
// K accumulation order unchanged -> bit-identical. Wave blocking 64x64 (R5).
// Occupancy is register-capped at 4 blocks/CU (64 VGPR + 64 AGPR acc).
#define CSH 136   // u16 col stride: 272B -> b128-aligned, window starts spread over banks
__global__ __launch_bounds__(256, 4) void gram_sel_kernel(const _Float16* __restrict__ fn,
                                                          uint32_t* __restrict__ top) {
    __shared__ __align__(16) char smem[128 * CSH * 2];   // 34816 B (pipeline uses 32768)
    unsigned short* Ch = (unsigned short*)smem;          // col-major u16 tile (selection)
    uint32_t* Ms = (uint32_t*)smem;                      // pair-merge staging

    const int t    = threadIdx.x;
    const int lane = t & 63;
    const int w    = t >> 6;
    const int m16  = lane & 15;
    const int q    = lane >> 4;
    const int wm   = w & 1;          // row half (0..1)
    const int wn   = w >> 1;         // col half (0..1)

    // XCD-aware bijective swizzle: grid 2112 = 8 * 264
    const int bid0 = blockIdx.x;
    const int bid  = (bid0 & 7) * 264 + (bid0 >> 3);

    // triangular block index -> (b, it, jt) with it <= jt
    const int b = bid / TRI;
    const int u = bid - b * TRI;
    int it = (int)(32.5f - sqrtf(32.5f * 32.5f - 2.0f * (float)u));
    while (u >= (it + 1) * (65 - (it + 1)) / 2) ++it;
    while (u < it * (65 - it) / 2) --it;
    const int jt = it + (u - it * (65 - it) / 2);
    const bool diag = (it == jt);

    const int i0 = it * 128, j0 = jt * 128;
    const _Float16* fnb = fn + (size_t)b * N_ * C_;

    floatx4 acc[4][4];
#pragma unroll
    for (int mi = 0; mi < 4; ++mi)
#pragma unroll
        for (int ni = 0; ni < 4; ++ni) acc[mi][ni] = floatx4{0.f, 0.f, 0.f, 0.f};

    // stage 32 channels (kc8) of A and B into buffer bsel: 4 gl_lds16 per thread
    auto stage = [&](int kc8, int bsel) {
        char* base = smem + bsel * 16384;
#pragma unroll
        for (int r = 0; r < 2; ++r) {
            const int L  = (t >> 3) + r * 32;          // 128B line (row-pair)
            const int sl = (t & 7) ^ (L & 7);          // logical slot for my dest
            const int row = 2 * L + (sl >> 2);
            const int c   = sl & 3;
            const _Float16* gA = fnb + (size_t)(i0 + row) * C_ + kc8 * 32 + c * 8;
            const _Float16* gB = fnb + (size_t)(j0 + row) * C_ + kc8 * 32 + c * 8;
            gl_lds16(gA, base + r * 4096 + t * 16);
            gl_lds16(gB, base + 8192 + r * 4096 + t * 16);
        }
    };
    auto compute = [&](int bsel) {
        const char* Asb = smem + bsel * 16384;
        const char* Bsb = Asb + 8192;
        half8 af[4], bf[4];
#pragma unroll
        for (int mi = 0; mi < 4; ++mi) {
            const int row = wm * 64 + mi * 16 + m16;
            const int R = row >> 1;
            const int slot = (((row & 1) << 2) | q) ^ (R & 7);
            af[mi] = *(const half8*)(Asb + R * 128 + slot * 16);
        }
#pragma unroll
        for (int ni = 0; ni < 4; ++ni) {
            const int row = wn * 64 + ni * 16 + m16;
            const int R = row >> 1;
            const int slot = (((row & 1) << 2) | q) ^ (R & 7);
            bf[ni] = *(const half8*)(Bsb + R * 128 + slot * 16);
        }
#pragma unroll
        for (int mi = 0; mi < 4; ++mi)
#pragma unroll
            for (int ni = 0; ni < 4; ++ni)
                acc[mi][ni] = __builtin_amdgcn_mfma_f32_16x16x32_f16(af[mi], bf[ni], acc[mi][ni], 0, 0, 0);
    };

    stage(0, 0);
    stage(1, 1);
    asm volatile("s_waitcnt vmcnt(4)" ::: "memory");   // my buf0 loads landed
    pipe_barrier();                                     // everyone's buf0 landed
#pragma unroll
    for (int s = 0; s < 8; ++s) {
        compute(s & 1);
        pipe_barrier();                                 // all waves done READING buf
        if (s < 6) {
            stage(s + 2, s & 1);                        // overwrite just-freed buffer
            asm volatile("s_waitcnt vmcnt(4)" ::: "memory");  // next buf landed (mine)
            pipe_barrier();                             // next buf landed (all)
        } else if (s == 6) {
            asm volatile("s_waitcnt vmcnt(0)" ::: "memory");  // tail drain (last buf)
            pipe_barrier();
        }
    }

    // ---- dump tile col-major as flipped u16, row-quads via cvt_pkrtz + b64 ----
    // C/D layout: col = wn*64 + ni*16 + m16, rows = wm*64 + mi*16 + q*4 + {0..3}
#pragma unroll
    for (int ni = 0; ni < 4; ++ni)
#pragma unroll
        for (int mi = 0; mi < 4; ++mi) {
            const int col = wn * 64 + ni * 16 + m16;
            const int row = wm * 64 + mi * 16 + q * 4;
            uint32_t fl[2];
#pragma unroll
            for (int p = 0; p < 2; ++p) {
                auto pk2 = __builtin_amdgcn_cvt_pkrtz(acc[mi][ni][2 * p], acc[mi][ni][2 * p + 1]);
                uint32_t bits = __builtin_bit_cast(uint32_t, pk2);
                uint32_t s = (bits >> 15) & 0x00010001u;
                fl[p] = bits ^ (s * 0x7FFFu + 0x80008000u);   // per-half order-flip
            }
            *(uint2*)&Ch[col * CSH + row] = make_uint2(fl[0], fl[1]);
        }
    __syncthreads();

    // ---- contiguous col-scan (always): 2 threads/col, 64 rows each, b128 reads ----
    // packed idx = global ROW index. Off-diag: j-side partials; diag: == row result.
    uint32_t cpk[8], rpk[8];
    {
        const int ccol = t >> 1, cr0 = (t & 1) * 64;
        const unsigned short* cc = &Ch[ccol * CSH + cr0];
        const int ibase = i0 + cr0;
#pragma unroll
        for (int g = 0; g < 8; ++g) {
            ushort8 v = *(const ushort8*)(cc + g * 8);
            uint32_t cand[8];
#pragma unroll
            for (int e = 0; e < 8; ++e)
                cand[e] = ((uint32_t)v[e] << 16) | (uint32_t)(ibase + g * 8 + e);
            sort8(cand);
            if (g == 0) {
#pragma unroll
                for (int s = 0; s < 8; ++s) cpk[s] = cand[s];
            } else merge8(cpk, cand);
        }
    }
    // ---- strided row-scan (off-diag only): 2 threads/row, 64 cols each ----
    if (!diag) {
        const int rrow = t >> 1, ch0 = (t & 1) * 64;
        const unsigned short* cr = &Ch[ch0 * CSH + rrow];
        const int jbase = j0 + ch0;
#pragma unroll
        for (int g = 0; g < 8; ++g) {
            uint32_t cand[8];
#pragma unroll
            for (int e = 0; e < 8; ++e)
                cand[e] = ((uint32_t)cr[(g * 8 + e) * CSH] << 16) | (uint32_t)(jbase + g * 8 + e);
            sort8(cand);
            if (g == 0) {
#pragma unroll
                for (int s = 0; s < 8; ++s) rpk[s] = cand[s];
            } else merge8(rpk, cand);
        }
    }
    __syncthreads();   // done reading Ch; reuse as merge staging

    // ---- pair-merge across the 2 threads of each col/row, emit 8 u32 ----
    if (t & 1) {
#pragma unroll
        for (int s = 0; s < 8; ++s) Ms[(t >> 1) * 8 + s] = cpk[s];
        if (!diag) {
#pragma unroll
            for (int s = 0; s < 8; ++s) Ms[1024 + (t >> 1) * 8 + s] = rpk[s];
        }
    }
    __syncthreads();
    if (!(t & 1)) {
        uint32_t o[8];
#pragma unroll
        for (int s = 0; s < 8; ++s) o[s] = Ms[(t >> 1) * 8 + s];
        merge8(cpk, o);
        uint32_t* dst = top + (((size_t)b * N_ + j0 + (t >> 1)) * 32 + it) * 8;
        *(uint4*)dst       = make_uint4(cpk[0], cpk[1], cpk[2], cpk[3]);
        *(uint4*)(dst + 4) = make_uint4(cpk[4], cpk[5], cpk[6], cpk[7]);
        if (!diag) {
#pragma unroll
            for (int s = 0; s < 8; ++s) o[s] = Ms[1024 + (t >> 1) * 8 + s];
            merge8(rpk, o);
            uint32_t* dst2 = top + (((size_t)b * N_ + i0 + (t >> 1)) * 32 + jt) * 8;
            *(uint4*)dst2       = make_uint4(rpk[0], rpk[1], rpk[2], rpk[3]);
            *(uint4*)(dst2 + 4) = make_uint4(rpk[4], rpk[5], rpk[6], rpk[7]);
        }
    }
}

// ---------------- Kernel 3: merge 32 partials/row, gather prob, partial loss ----------------
// NOTE: plain stores + separate final reduce. Do NOT use acq_rel agent atomics here:
// round 10 showed they emit per-block L2 writeback/invalidate -> 90 µs (10x regression).
__global__ __launch_bounds__(256) void merge_kernel(const uint32_t* __restrict__ top,
                                                    const float* __restrict__ prob,
                                                    float* __restrict__ partials) {
    __shared__ float red[4];
    const int t = threadIdx.x;
    const int lane = t & 63;
    const int w = t >> 6;
    const int rg = blockIdx.x * 4 + w;             // 0..16383
    const int b = rg >> 12;

    uint4 v4 = ((const uint4*)(top + (size_t)rg * 256))[lane];
    uint32_t v[4] = {v4.x, v4.y, v4.z, v4.w};
    uint32_t m = max(max(v[0], v[1]), max(v[2], v[3]));

    const float* pb = prob + (b << 12);
    float p_r = prob[rg];
    float contrib = 0.f;
#pragma unroll
    for (int k = 0; k < 8; ++k) {
        uint32_t M = m;
#pragma unroll
        for (int off = 32; off; off >>= 1) M = max(M, (uint32_t)__shfl_xor((int)M, off));
        if (lane == k) contrib = fabsf(p_r - pb[M & 0xFFFu]);
#pragma unroll
        for (int s = 0; s < 4; ++s) v[s] = (v[s] == M) ? 0u : v[s];
        m = max(max(v[0], v[1]), max(v[2], v[3]));
    }
#pragma unroll
    for (int off = 32; off; off >>= 1) contrib += __shfl_xor(contrib, off);
    if (lane == 0) red[w] = contrib;
    __syncthreads();
    if (t == 0) partials[blockIdx.x] = red[0] + red[1] + red[2] + red[3];
}

// ---------------- Kernel 4: final reduce (4096 partials) ----------------
__global__ __launch_bounds__(256) void final_kernel(const float* __restrict__ partials,
                                                    float* __restrict__ out) {
    __shared__ float red[256];
    int t = threadIdx.x;
    float s = 0.f;
#pragma unroll
    for (int k = 0; k < 16; ++k) s += partials[k * 256 + t];
    red[t] = s;
    __syncthreads();
    for (int off = 128; off > 0; off >>= 1) {
        if (t < off) red[t] += red[t + off];
        __syncthreads();
    }
    if (t == 0) out[0] = red[0] * (1.f / (B_ * N_ * 8.0f));
}

extern "C" void kernel_launch(void* const* d_in, const int* in_sizes, int n_in,
                              void* d_out, int out_size, void* d_ws, size_t ws_size,
                              hipStream_t stream) {
    const float* feats  = (const float*)d_in[0];
    const float* logits = (const float*)d_in[1];
    float* out = (float*)d_out;
    char* ws = (char*)d_ws;
    _Float16* fn   = (_Float16*)(ws + OFF_FN);
    float* prob    = (float*)(ws + OFF_PROB);
    float* parts   = (float*)(ws + OFF_PART);
    uint32_t* top  = (uint32_t*)(ws + OFF_TOP);

    prep_kernel<<<256, 256, 0, stream>>>(feats, logits, fn, prob);
    gram_sel_kernel<<<B_ * TRI, 256, 0, stream>>>(fn, top);
    merge_kernel<<<4096, 256, 0, stream>>>(top, prob, parts);
    final_kernel<<<1, 256, 0, stream>>>(parts, out);
}